// Round 1
// baseline (680.662 us; speedup 1.0000x reference)
//
#include <hip/hip_runtime.h>

// AgentLSM CPG/LIF forward, B=524288, N=32 neurons, 5 ticks.
// R3: grid-stride persistent blocks (2048 x 32 chunks of 8 batch elems).
//   - coupling_W rows live in VGPRs (28 regs, zero-padded), loaded once per
//     block from global (L2-resident after first touch) -> removes 25
//     ds_read_b32/thread/chunk and the per-block W LDS staging.
//   - per-group neighbor counts padded to 28 floats (112 B = 7 float4,
//     16B-aligned per group) and read as 7 ds_read_b128 broadcasts instead
//     of 25 ds_read_b32. Pads written 0.0 so w_pad*cnt_pad == 0 exactly.
//   LDS issue-pipe per chunk drops ~1500 -> ~700 cyc, below the ~1100-cyc
//   HBM-parity budget -> kernel becomes BW-bound (~85-95 us).
// Carried from R2: ballot spike masks, 2-popcount recurrent, v0==0 skip,
// LDS-staged float4 outputs, T==5 unroll.

#define FATIGUE_TH 8

__global__ __launch_bounds__(256) void AgentLSM_70841190580507_kernel(
    const float* __restrict__ sh_in,     // [B,32]  spike_history
    const float* __restrict__ nbr,       // [B,8,25] neighbor_E_spikes
    const float* __restrict__ M,         // [32,32] mutual_inhibition
    const float* __restrict__ W,         // [32,25] coupling_W
    const int*   __restrict__ pf,        // [B] peak_fatigue
    const int*   __restrict__ tf,        // [B] trough_fatigue
    const int*   __restrict__ ticks_p,   // [1] num_ticks
    float* __restrict__ out_acc,         // [B,25]
    float* __restrict__ out_stay,        // [B]
    int B, int nchunks)
{
    __shared__ float4 lds_nbr4[400];    // 8 b * 200 floats, coalesced staging
    __shared__ float  lds_cnt[8 * 28];  // per-b k-reduced counts, padded to 28
    __shared__ float  lds_out[200];     // 8 b * 25 acc, staged for float4 writes
    __shared__ float  lds_stay[8];

    float* lds_nbr = (float*)lds_nbr4;

    const int tid = threadIdx.x;
    const int g   = tid >> 5;          // local batch element 0..7
    const int m   = tid & 31;          // neuron index
    const bool is_peak = (m < 16);

    // W row of this neuron -> 28 VGPRs (zero-padded). Once per block;
    // 3.2 KB table is L1/L2-resident, cost amortized over 32 chunks.
    float w[28];
    #pragma unroll
    for (int n = 0; n < 25; ++n) w[n] = W[m * 25 + n];
    w[25] = 0.f; w[26] = 0.f; w[27] = 0.f;

    const float a_same  = M[0];   // -0.2 within-population
    const float a_cross = M[16];  // -3.0 cross-population
    const int T = ticks_p[0];

    for (int chunk = blockIdx.x; chunk < nchunks; chunk += gridDim.x) {
        const long long b = (long long)chunk * 8 + g;
        const int nv = min(8, B - chunk * 8);   // valid elems in this chunk
        const bool valid = (g < nv);

        // ---- stage this chunk's neighbor spikes into LDS, coalesced float4
        const float4* nb4 = (const float4*)nbr + (long long)chunk * 400;
        if (nv == 8) {
            #pragma unroll
            for (int i = tid; i < 400; i += 256) lds_nbr4[i] = nb4[i];
        } else {
            const long long ftot  = (long long)B * 200;
            const long long fbase = (long long)chunk * 1600;
            for (int i = tid; i < 400; i += 256) {
                long long f0 = fbase + (long long)i * 4;
                lds_nbr4[i] = (f0 + 3 < ftot) ? nb4[i]
                                              : make_float4(0.f, 0.f, 0.f, 0.f);
            }
        }

        // per-b scalars overlap with staging latency
        float drive = 0.f;
        int init_bit = 0;
        if (valid) {
            drive = is_peak ? ((tf[b] >= FATIGUE_TH) ? 2.0f : 0.0f)
                            : ((pf[b] >= FATIGUE_TH) ? 2.0f : 0.0f);
            init_bit = (sh_in[b * 32 + m] != 0.0f);
        }

        __syncthreads();   // A: nbr staged

        // cnt[n] = sum_k nbr[b,k,n]; pads 25..27 explicitly zeroed
        if (m < 28) {
            float c = 0.f;
            if (m < 25) {
                #pragma unroll
                for (int k = 0; k < 8; ++k) c += lds_nbr[g * 200 + k * 25 + m];
            }
            lds_cnt[g * 28 + m] = c;
        }

        __syncthreads();   // B: cnt visible

        // coupling[m] = dot(cnt, W[m,:]) — 7 b128 broadcast reads + reg W
        float coup = 0.f;
        {
            const float4* c4p = (const float4*)&lds_cnt[g * 28]; // 112B-aligned
            #pragma unroll
            for (int q = 0; q < 7; ++q) {
                float4 c4 = c4p[q];
                coup += c4.x * w[4*q+0] + c4.y * w[4*q+1]
                      + c4.z * w[4*q+2] + c4.w * w[4*q+3];
            }
        }

        const float base = drive + 0.3f * coup;
        float v = 0.0f;                  // v0 is zeros by construction

        unsigned long long bal = __ballot(init_bit);
        unsigned int mask = (unsigned int)(bal >> (tid & 32));

        int acc = 0;
        unsigned int any_tr = 0;

        #define TICK()  do {                                                   \
            float Spf = (float)__popc(mask & 0xFFFFu);                         \
            float Stf = (float)__popc(mask >> 16);                             \
            float rec = is_peak ? (a_same * Spf + a_cross * Stf)               \
                                : (a_cross * Spf + a_same * Stf);              \
            float x = base + 0.5f * rec;                                       \
            v = v + (x - v) / 3.0f;            /* LIF, IEEE div by tau */      \
            bool s = (v >= 1.0f);              /* == (v-1.0 >= 0) exactly */   \
            unsigned long long sb = __ballot(s);                               \
            mask = (unsigned int)(sb >> (tid & 32));                           \
            any_tr |= (mask >> 16);                                            \
            acc += s ? 1 : 0;                                                  \
            v = s ? 0.0f : v;                                                  \
        } while (0)

        if (T == 5) {
            TICK(); TICK(); TICK(); TICK(); TICK();
        } else {
            for (int t = 0; t < T; ++t) TICK();
        }
        #undef TICK

        // ---- stage outputs to LDS for coalesced float4 stores
        if (m < 25) lds_out[g * 25 + m] = (float)acc;
        if (m == 31) lds_stay[g] = any_tr ? 1.0f : 0.0f;
        __syncthreads();   // C: out staged (also fences lds_nbr for next chunk)

        const long long obase = (long long)chunk * 200;
        if (nv == 8) {
            if (tid < 50)
                ((float4*)out_acc)[obase / 4 + tid] =
                    ((const float4*)lds_out)[tid];
            if (tid < 8)
                out_stay[(long long)chunk * 8 + tid] = lds_stay[tid];
        } else {
            if (tid < nv * 25) out_acc[obase + tid] = lds_out[tid];
            if (tid < nv)      out_stay[(long long)chunk * 8 + tid] = lds_stay[tid];
        }
        // no extra barrier needed: next chunk's writes to lds_nbr are
        // consumed only after next sync A; lds_out rewritten after next sync B.
    }
}

extern "C" void kernel_launch(void* const* d_in, const int* in_sizes, int n_in,
                              void* d_out, int out_size, void* d_ws, size_t ws_size,
                              hipStream_t stream) {
    const float* sh    = (const float*)d_in[0];
    const float* nbr   = (const float*)d_in[1];
    const float* M     = (const float*)d_in[2];
    const float* W     = (const float*)d_in[3];
    const int*   pf    = (const int*)d_in[5];
    const int*   tf    = (const int*)d_in[6];
    const int*   ticks = (const int*)d_in[7];

    const int B = in_sizes[5];           // peak_fatigue is [B]
    float* out_acc  = (float*)d_out;
    float* out_stay = out_acc + (long long)B * 25;

    const int nchunks = (B + 7) / 8;
    // persistent grid-stride: 2048 blocks (~8 per CU), 32 chunks each at B=512k
    int blocks = nchunks < 2048 ? nchunks : 2048;
    AgentLSM_70841190580507_kernel<<<blocks, 256, 0, stream>>>(
        sh, nbr, M, W, pf, tf, ticks, out_acc, out_stay, B, nchunks);
}

// Round 3
// 636.936 us; speedup vs baseline: 1.0686x; 1.0686x over previous
//
#include <hip/hip_runtime.h>

// AgentLSM CPG/LIF forward, B=524288, N=32 neurons, 5 ticks.
// R4 (resubmit — R2 bench was a GPUAcquisitionTimeout, no data):
// persistent blocks (8192 x 8 chunks) WITH double-buffered async prefetch.
//   R3 post-mortem: persistence without prefetch exposed ~900cyc HBM latency
//   per chunk (loads issued after the consuming barrier). Fix:
//   - nbr staged via __builtin_amdgcn_global_load_lds (16B DMA, no VGPR trip)
//     into 2 LDS buffers; prefetch of chunk i+1 issues right AFTER sync1 so
//     the coupling+ticks+stores phase covers the latency before sync2's
//     implicit vmcnt(0) drain.
//   - W rows in VGPRs (28 regs, zero-padded), bootstrapped once per block via
//     a coalesced LDS pass (stride-25 reads are bank-conflict-free). Removes
//     the 25 ds_read_b32/thread/chunk that dominated the LDS pipe.
//   - coupling reads cnt as 7 ds_read_b128 broadcasts (lds_cnt padded to 28).
//   - outputs stored directly (contiguous per block, L2 write-combines);
//     lds_out/lds_W and the third barrier are gone. 2 barriers per chunk.
// Carried: ballot spike masks, 2-popcount recurrent, v0==0 skip, T==5 unroll.

#define FATIGUE_TH 8

__device__ __forceinline__ void async_f4(const float* g, float* l) {
    __builtin_amdgcn_global_load_lds(
        (const __attribute__((address_space(1))) void*)g,
        (__attribute__((address_space(3))) void*)l, 16, 0, 0);
}

__global__ __launch_bounds__(256, 4) void AgentLSM_70841190580507_kernel(
    const float* __restrict__ sh_in,     // [B,32]  spike_history
    const float* __restrict__ nbr,       // [B,8,25] neighbor_E_spikes
    const float* __restrict__ M,         // [32,32] mutual_inhibition
    const float* __restrict__ W,         // [32,25] coupling_W
    const int*   __restrict__ pf,        // [B] peak_fatigue
    const int*   __restrict__ tf,        // [B] trough_fatigue
    const int*   __restrict__ ticks_p,   // [1] num_ticks
    float* __restrict__ out_acc,         // [B,25]
    float* __restrict__ out_stay,        // [B]
    int B, int nchunks, int cpb)
{
    __shared__ float lds_nbr[2][1600];  // 2 x 8 b x 200 floats (12.8 KB)
    __shared__ float lds_cnt[8 * 28];   // per-b counts, padded to 28 (float4)

    const int tid = threadIdx.x;
    const int g   = tid >> 5;           // local batch element 0..7
    const int m   = tid & 31;           // neuron index
    const bool is_peak = (m < 16);

    // ---- bootstrap: W -> VGPRs via one coalesced LDS pass (buf0 reused)
    if (tid < 200) async_f4(W + tid * 4, &lds_nbr[0][tid * 4]);
    __syncthreads();                    // DMA drained by implicit vmcnt(0)
    float w[28];
    #pragma unroll
    for (int n = 0; n < 25; ++n) w[n] = lds_nbr[0][m * 25 + n]; // stride 25: conflict-free
    w[25] = 0.f; w[26] = 0.f; w[27] = 0.f;
    const float a_same  = M[0];   // -0.2 within-population
    const float a_cross = M[16];  // -3.0 cross-population
    const int T = ticks_p[0];
    __syncthreads();                    // done using buf0 as W scratch

    const int first = blockIdx.x * cpb;
    if (first >= nchunks) return;
    const int count = min(cpb, nchunks - first);

    // ---- stage helper: chunk c -> lds_nbr[buf]
    #define STAGE(c, buf) do {                                                \
        const float* _src = nbr + (long long)(c) * 1600;                      \
        float* _dst = lds_nbr[(buf)];                                         \
        if ((long long)((c) + 1) * 8 <= (long long)B) {                       \
            async_f4(_src + tid * 4, _dst + tid * 4);                         \
            if (tid < 144) async_f4(_src + (tid + 256) * 4,                   \
                                    _dst + (tid + 256) * 4);                  \
        } else {            /* partial tail chunk: guarded reg staging */     \
            const long long _ftot = (long long)B * 200 - (long long)(c) * 1600;\
            for (int _i = tid; _i < 400; _i += 256) {                         \
                float4 _v = make_float4(0.f, 0.f, 0.f, 0.f);                  \
                if ((long long)_i * 4 + 3 < _ftot)                            \
                    _v = ((const float4*)_src)[_i];                           \
                ((float4*)_dst)[_i] = _v;                                     \
            }                                                                 \
        }                                                                     \
    } while (0)

    STAGE(first, 0);
    __syncthreads();                    // chunk0 resident

    int cur = 0;
    for (int j = 0; j < count; ++j) {
        const int c = first + j;
        const long long b = (long long)c * 8 + g;
        const bool valid = (b < (long long)B);

        // per-b global scalars issue early (covered by cnt phase)
        float drive = 0.f;
        int init_bit = 0;
        if (valid) {
            drive = is_peak ? ((tf[b] >= FATIGUE_TH) ? 2.0f : 0.0f)
                            : ((pf[b] >= FATIGUE_TH) ? 2.0f : 0.0f);
            init_bit = (sh_in[b * 32 + m] != 0.0f);
        }

        // cnt[n] = sum_k nbr[b,k,n]; pads 25..27 zeroed (stride-25 reads <=2-way)
        if (m < 28) {
            float cv = 0.f;
            if (m < 25) {
                #pragma unroll
                for (int k = 0; k < 8; ++k) cv += lds_nbr[cur][g * 200 + k * 25 + m];
            }
            lds_cnt[g * 28 + m] = cv;
        }
        __syncthreads();   // sync1: cnt visible; drains only the small scalar loads

        // prefetch next chunk NOW: covered by coupling+ticks+stores until sync2
        if (j + 1 < count) STAGE(c + 1, cur ^ 1);

        // coupling[m] = dot(cnt, W[m,:]) — 7 b128 broadcast reads + reg W
        float coup = 0.f;
        {
            const float4* c4p = (const float4*)&lds_cnt[g * 28]; // 112B-aligned
            #pragma unroll
            for (int q = 0; q < 7; ++q) {
                float4 c4 = c4p[q];
                coup += c4.x * w[4*q+0] + c4.y * w[4*q+1]
                      + c4.z * w[4*q+2] + c4.w * w[4*q+3];
            }
        }

        const float base = drive + 0.3f * coup;
        float v = 0.0f;                  // v0 is zeros by construction

        unsigned long long bal = __ballot(init_bit);
        unsigned int mask = (unsigned int)(bal >> (tid & 32));

        int acc = 0;
        unsigned int any_tr = 0;

        #define TICK()  do {                                                   \
            float Spf = (float)__popc(mask & 0xFFFFu);                         \
            float Stf = (float)__popc(mask >> 16);                             \
            float rec = is_peak ? (a_same * Spf + a_cross * Stf)               \
                                : (a_cross * Spf + a_same * Stf);              \
            float x = base + 0.5f * rec;                                       \
            v = v + (x - v) / 3.0f;            /* LIF, IEEE div by tau */      \
            bool s = (v >= 1.0f);              /* == (v-1.0 >= 0) exactly */   \
            unsigned long long sb = __ballot(s);                               \
            mask = (unsigned int)(sb >> (tid & 32));                           \
            any_tr |= (mask >> 16);                                            \
            acc += s ? 1 : 0;                                                  \
            v = s ? 0.0f : v;                                                  \
        } while (0)

        if (T == 5) {
            TICK(); TICK(); TICK(); TICK(); TICK();
        } else {
            for (int t = 0; t < T; ++t) TICK();
        }
        #undef TICK

        // direct stores: block's acc covers contiguous 800B/chunk -> L2 combines
        if (valid) {
            if (m < 25) out_acc[(long long)c * 200 + g * 25 + m] = (float)acc;
            if (m == 0) out_stay[b] = any_tr ? 1.0f : 0.0f;
        }

        __syncthreads();   // sync2: drains prefetch DMA; fences lds_cnt reuse
        cur ^= 1;
    }
    #undef STAGE
}

extern "C" void kernel_launch(void* const* d_in, const int* in_sizes, int n_in,
                              void* d_out, int out_size, void* d_ws, size_t ws_size,
                              hipStream_t stream) {
    const float* sh    = (const float*)d_in[0];
    const float* nbr   = (const float*)d_in[1];
    const float* M     = (const float*)d_in[2];
    const float* W     = (const float*)d_in[3];
    const int*   pf    = (const int*)d_in[5];
    const int*   tf    = (const int*)d_in[6];
    const int*   ticks = (const int*)d_in[7];

    const int B = in_sizes[5];           // peak_fatigue is [B]
    float* out_acc  = (float*)d_out;
    float* out_stay = out_acc + (long long)B * 25;

    const int nchunks = (B + 7) / 8;     // 8 batch elems per chunk
    int grid = nchunks < 8192 ? nchunks : 8192;
    int cpb  = (nchunks + grid - 1) / grid;     // chunks per block (8 at B=512k)
    grid = (nchunks + cpb - 1) / cpb;
    AgentLSM_70841190580507_kernel<<<grid, 256, 0, stream>>>(
        sh, nbr, M, W, pf, tf, ticks, out_acc, out_stay, B, nchunks, cpb);
}